// Round 1
// 1135.968 us; speedup vs baseline: 1.4046x; 1.4046x over previous
//
#include <hip/hip_runtime.h>

#define NB   8
#define BS   96
#define CC   768
#define BB   2
#define HH   256
#define WW   256
#define YK   103            // kept_modes along W-freq
#define XLO  26             // band lo along H-freq
#define XHI  232            // band hi (exclusive)
#define NX   206            // band height
#define NP   (YK*NX)        // 21218 positions per (b,block,channel)
#define NTILE3 166          // ceil(NP/128)
#define NT3G  32            // k3 grid-stride width (tiles per sweep)

typedef float  f32x4  __attribute__((ext_vector_type(4)));
typedef __bf16 bf16x8 __attribute__((ext_vector_type(8)));

struct c32 { float re, im; };
__device__ __forceinline__ c32 cadd(c32 a, c32 b){ return {a.re+b.re, a.im+b.im}; }
__device__ __forceinline__ c32 csub(c32 a, c32 b){ return {a.re-b.re, a.im-b.im}; }
__device__ __forceinline__ c32 cmul(c32 a, c32 b){ return {a.re*b.re - a.im*b.im, a.re*b.im + a.im*b.re}; }
__device__ __forceinline__ c32 mulpi(c32 a){ return {-a.im,  a.re}; }   // *(+i)
__device__ __forceinline__ c32 mulni(c32 a){ return { a.im, -a.re}; }   // *(-i)

template<bool INV>
__device__ __forceinline__ void dft4(c32& a, c32& b, c32& c, c32& d){
  c32 s0 = cadd(a,c), s1 = csub(a,c), s2 = cadd(b,d), s3 = csub(b,d);
  c32 t3 = INV ? mulpi(s3) : mulni(s3);
  a = cadd(s0,s2); c = csub(s0,s2);
  b = cadd(s1,t3); d = csub(s1,t3);
}

__device__ __forceinline__ constexpr int fslot(int K){ return ((K&3)<<2)|(K>>2); }

template<bool INV>
__device__ __forceinline__ c32 w16mul(c32 a, int e){
  float c, s;
  switch(e){
    case 1: c= 0.9238795325112867f; s= 0.3826834323650898f; break;
    case 2: c= 0.7071067811865476f; s= 0.7071067811865476f; break;
    case 3: c= 0.3826834323650898f; s= 0.9238795325112867f; break;
    case 4: c= 0.0f;                s= 1.0f;                break;
    case 6: c=-0.7071067811865476f; s= 0.7071067811865476f; break;
    case 9: c=-0.9238795325112867f; s=-0.3826834323650898f; break;
    default: return a;
  }
  c32 w = { c, INV ? s : -s };       // forward: cos - i sin ; inverse: conj
  return cmul(a, w);
}

template<bool INV>
__device__ __forceinline__ void fft16(c32 v[16]){
  #pragma unroll
  for (int n2=0;n2<4;n2++) dft4<INV>(v[n2], v[n2+4], v[n2+8], v[n2+12]);
  #pragma unroll
  for (int k1=1;k1<4;k1++)
    #pragma unroll
    for (int n2=1;n2<4;n2++)
      v[n2+4*k1] = w16mul<INV>(v[n2+4*k1], k1*n2);
  #pragma unroll
  for (int k1=0;k1<4;k1++) dft4<INV>(v[4*k1], v[4*k1+1], v[4*k1+2], v[4*k1+3]);
  // output X[K] lives at slot fslot(K)
}

// 256-pt FFT done by 16 lanes (u = 0..15) of one team, all within one wave.
// buf: the team's private 272-float2 segment. Stage-1 reads natural order
// (stride 16), transposed+twiddled results go back IN PLACE at stride 17
// (pad kills bank conflicts). No workgroup barrier needed: a team is 16
// lanes of a single wave, and same-wave DS ops execute in order; every
// transposed write is also data-dependent on all 16 stage-1 reads.
template<bool INV>
__device__ __forceinline__ void fft256_team_u(const float2* __restrict__ tw,
                                              float2* __restrict__ buf,
                                              int u, c32 out[16]){
  c32 v[16];
  #pragma unroll
  for (int n1=0;n1<16;n1++){ float2 t = buf[16*n1 + u]; v[n1] = {t.x, t.y}; }
  fft16<INV>(v);
  #pragma unroll
  for (int k1=0;k1<16;k1++){
    c32 a = v[fslot(k1)];
    float2 t = tw[(u*k1) & 255];
    c32 w = { t.x, INV ? -t.y : t.y };
    a = cmul(a, w);
    buf[k1*17 + u] = make_float2(a.re, a.im);
  }
  __builtin_amdgcn_wave_barrier();   // pin compiler ordering; HW DS is in-order per wave
  c32 g[16];
  #pragma unroll
  for (int n2=0;n2<16;n2++){ float2 t = buf[u*17 + n2]; g[n2] = {t.x, t.y}; }
  fft16<INV>(g);
  #pragma unroll
  for (int k2=0;k2<16;k2++) out[k2] = g[fslot(k2)];
}

__device__ __forceinline__ unsigned pack_bf16(float r, float i){
  unsigned ur = __float_as_uint(r); ur += 0x7FFFu + ((ur >> 16) & 1u);
  unsigned ui = __float_as_uint(i); ui += 0x7FFFu + ((ui >> 16) & 1u);
  return (ur >> 16) | (ui & 0xFFFF0000u);
}
__device__ __forceinline__ float2 unpack_bf16(unsigned q){
  return make_float2(__uint_as_float(q << 16), __uint_as_float(q & 0xFFFF0000u));
}
__device__ __forceinline__ unsigned short bf16b(float f){
  unsigned u = __float_as_uint(f); u += 0x7FFFu + ((u >> 16) & 1u);
  return (unsigned short)(u >> 16);
}

__device__ __forceinline__ void build_tw(float2* tw, int tid){
  if (tid < 256){
    float s, c;
    sincosf(-6.2831853071795864769f * (float)tid / 256.0f, &s, &c);
    tw[tid] = make_float2(c, s);   // e^{-2pi i tid/256}
  }
}

// ---------------- K1: row rFFT along W via real-pair packing -----------------
// Two real rows per 256-pt complex FFT: Z = row_a + i*row_b, then
// A[k]=(Z[k]+conj(Z[256-k]))/2, B[k]=(Z[k]-conj(Z[256-k]))/(2i).
// 8 rounds of 32 rows (16 teams x 2 rows). LDS 50.5 KB -> 3 WG/CU.
__global__ __launch_bounds__(256, 3) void k1_rowfft(const float* __restrict__ x,
                                                    unsigned* __restrict__ I1){
  __shared__ float2   tw[256];
  __shared__ float2   buf[16*272];
  __shared__ unsigned trans[YK*33];
  int tid = threadIdx.x;
  build_tw(tw, tid);
  int wg = blockIdx.x; int b = wg / CC, c = wg % CC;
  const float* xp = x  + (size_t)(b*CC + c) * (HH*WW);
  unsigned*    op = I1 + (size_t)(b*CC + c) * (YK*HH);
  int team = tid >> 4, u = tid & 15;
  for (int r = 0; r < 8; ++r){
    __syncthreads();                       // prev round's buf reads / trans reads done
    #pragma unroll
    for (int j = 0; j < 16; ++j){
      float ra = xp[(r*32 + 2*j    )*WW + tid];
      float rb = xp[(r*32 + 2*j + 1)*WW + tid];
      buf[j*272 + tid] = make_float2(ra, rb);
    }
    __syncthreads();
    c32 out[16];
    fft256_team_u<false>(tw, buf + team*272, u, out);
    // separation + 1/256 ortho scale (0.5 folded in)
    const float s = 0.5f/256.0f;
    #pragma unroll
    for (int k2 = 0; k2 < 7; ++k2){
      int y = u + 16*k2;
      c32 p = out[k2];
      float qre = __shfl(out[15-k2].re, (16-u)&15, 16);
      float qim = __shfl(out[15-k2].im, (16-u)&15, 16);
      if (u == 0){ qre = out[(16-k2)&15].re; qim = out[(16-k2)&15].im; }
      if (y < YK){
        float Are = (p.re + qre)*s, Aim = (p.im - qim)*s;
        float Bre = (p.im + qim)*s, Bim = (qre - p.re)*s;
        trans[y*33 + 2*team    ] = pack_bf16(Are, Aim);
        trans[y*33 + 2*team + 1] = pack_bf16(Bre, Bim);
      }
    }
    __syncthreads();
    for (int idx = tid; idx < YK*32; idx += 256){
      int y = idx >> 5, j = idx & 31;
      op[y*HH + r*32 + j] = trans[y*33 + j];
    }
  }
}

// ---------------- K2: column FFT along H, keep band rows -> band[b][k][i][y][x]
__global__ __launch_bounds__(256, 4) void k2_colfft(const unsigned* __restrict__ I1,
                                                    unsigned* __restrict__ band){
  __shared__ float2 tw[256];
  __shared__ float2 buf[16*272];
  int tid = threadIdx.x;
  build_tw(tw, tid);
  int wg = blockIdx.x; int b = wg / CC, c = wg % CC;
  int kb = c / BS, i = c % BS;
  const unsigned* ip = I1   + (size_t)(b*CC + c) * (YK*HH);
  unsigned*       op = band + (size_t)((b*NB + kb)*BS + i) * NP;
  int team = tid >> 4, u = tid & 15;
  for (int r = 0; r < 7; ++r){
    __syncthreads();
    for (int j = 0; j < 16; ++j){
      int y = r*16 + j;
      if (y < YK) buf[j*272 + tid] = unpack_bf16(ip[y*HH + tid]);
    }
    __syncthreads();
    c32 out[16];
    fft256_team_u<false>(tw, buf + team*272, u, out);
    int y = r*16 + team;
    if (y < YK){
      #pragma unroll
      for (int k2 = 0; k2 < 16; ++k2){
        int h = u + 16*k2;
        if (h >= XLO && h < XHI)
          op[y*NX + (h - XLO)] = pack_bf16(out[k2].re, out[k2].im);
      }
    }
  }
}

// ---------------- K3: per-block complex MLP (MFMA bf16), in-place on band ----
__device__ __forceinline__ bf16x8 ldfrag(const uint4* wf, int m, int nt, int kt, int ln){
  union { uint4 q; bf16x8 v; } uu;
  uu.q = wf[((m*6 + nt)*3 + kt)*64 + ln];
  return uu.v;
}
__device__ __forceinline__ void build_frags(const unsigned q[8], bf16x8& fr, bf16x8& fi, bf16x8& fn){
  union { unsigned u[4]; bf16x8 v; } ur, ui, un;
  #pragma unroll
  for (int m2 = 0; m2 < 4; ++m2){
    unsigned a0 = q[2*m2], a1 = q[2*m2+1];
    ur.u[m2] = (a0 & 0xFFFFu) | (a1 << 16);
    ui.u[m2] = (a0 >> 16)     | (a1 & 0xFFFF0000u);
    un.u[m2] = ui.u[m2] ^ 0x80008000u;
  }
  fr = ur.v; fi = ui.v; fn = un.v;
}

__global__ __launch_bounds__(256) void k3_mix(unsigned* __restrict__ band,
                                              const float* __restrict__ w1,
                                              const float* __restrict__ b1,
                                              const float* __restrict__ w2,
                                              const float* __restrict__ b2){
  __shared__ uint4    wfrag4[4*6*3*64];   // 73,728 B : W1r,W1i,W2r,W2i B-fragment swizzled
  __shared__ unsigned xbuf[128*97];       // 49,664 B : o1 / o2 tile, padded stride 97
  __shared__ float    biasL[4*96];        // b1r,b1i,b2r,b2i
  int tid  = threadIdx.x;
  int bk   = blockIdx.y;
  int b = bk >> 3, kb = bk & 7;

  unsigned short* wf = (unsigned short*)wfrag4;
  for (int idx = tid; idx < 4*9216; idx += 256){
    int m = idx / 9216, f = idx % 9216;
    int nt = f / 1536, g = f % 1536;
    int kt = g / 512,  h = g % 512;
    int lane = h >> 3, j = h & 7;
    int k = kt*32 + (lane >> 4)*8 + j;
    int n = nt*16 + (lane & 15);
    const float* src = (m < 2) ? w1 : w2;
    wf[idx] = bf16b(src[((kb*BS + k)*BS + n)*2 + (m & 1)]);
  }
  for (int idx = tid; idx < 4*96; idx += 256){
    int m = idx / 96, o = idx % 96;
    const float* src = (m < 2) ? b1 : b2;
    biasL[idx] = src[(kb*BS + o)*2 + (m & 1)];
  }
  __syncthreads();

  int wv = tid >> 6, ln = tid & 63;
  int col = ln & 15, quad = ln >> 4;
  unsigned* Abase = band + (size_t)((b*NB + kb)*BS) * NP;

  for (int tile = blockIdx.x; tile < NTILE3; tile += NT3G){
    int p0 = tile*128 + wv*32;

    // ---- layer 1 A fragments from global (band), packed (re,im) per uint
    bf16x8 Ar[2][3], Ai[2][3], An[2][3];
    #pragma unroll
    for (int mt = 0; mt < 2; ++mt){
      int p = p0 + mt*16 + col;
      bool ok = (p < NP);
      #pragma unroll
      for (int kt = 0; kt < 3; ++kt){
        unsigned q[8];
        #pragma unroll
        for (int j = 0; j < 8; ++j){
          int i = kt*32 + quad*8 + j;
          q[j] = ok ? Abase[(size_t)i*NP + p] : 0u;
        }
        build_frags(q, Ar[mt][kt], Ai[mt][kt], An[mt][kt]);
      }
    }

    f32x4 aR[6][2], aI[6][2];
    #pragma unroll
    for (int nt = 0; nt < 6; ++nt){
      float br = biasL[0*96 + nt*16 + col];
      float bi = biasL[1*96 + nt*16 + col];
      #pragma unroll
      for (int mt = 0; mt < 2; ++mt){
        aR[nt][mt] = (f32x4){br,br,br,br};
        aI[nt][mt] = (f32x4){bi,bi,bi,bi};
      }
    }
    #pragma unroll
    for (int nt = 0; nt < 6; ++nt)
      #pragma unroll
      for (int kt = 0; kt < 3; ++kt){
        bf16x8 Br = ldfrag(wfrag4, 0, nt, kt, ln);
        bf16x8 Bi = ldfrag(wfrag4, 1, nt, kt, ln);
        #pragma unroll
        for (int mt = 0; mt < 2; ++mt){
          aR[nt][mt] = __builtin_amdgcn_mfma_f32_16x16x32_bf16(Ar[mt][kt], Br, aR[nt][mt], 0,0,0);
          aR[nt][mt] = __builtin_amdgcn_mfma_f32_16x16x32_bf16(An[mt][kt], Bi, aR[nt][mt], 0,0,0);
          aI[nt][mt] = __builtin_amdgcn_mfma_f32_16x16x32_bf16(Ai[mt][kt], Br, aI[nt][mt], 0,0,0);
          aI[nt][mt] = __builtin_amdgcn_mfma_f32_16x16x32_bf16(Ar[mt][kt], Bi, aI[nt][mt], 0,0,0);
        }
      }
    // CReLU + store o1 to LDS (C-layout -> [p][o])
    #pragma unroll
    for (int nt = 0; nt < 6; ++nt)
      #pragma unroll
      for (int mt = 0; mt < 2; ++mt)
        #pragma unroll
        for (int rr = 0; rr < 4; ++rr){
          float vr = fmaxf(aR[nt][mt][rr], 0.0f);
          float vi = fmaxf(aI[nt][mt][rr], 0.0f);
          int pl = wv*32 + mt*16 + quad*4 + rr;
          xbuf[pl*97 + nt*16 + col] = pack_bf16(vr, vi);
        }
    __syncthreads();

    // ---- layer 2 A fragments from LDS
    bf16x8 Cr[2][3], Ci[2][3], Cn[2][3];
    #pragma unroll
    for (int mt = 0; mt < 2; ++mt){
      int pl = wv*32 + mt*16 + col;
      #pragma unroll
      for (int kt = 0; kt < 3; ++kt){
        unsigned q[8];
        #pragma unroll
        for (int j = 0; j < 8; ++j) q[j] = xbuf[pl*97 + kt*32 + quad*8 + j];
        build_frags(q, Cr[mt][kt], Ci[mt][kt], Cn[mt][kt]);
      }
    }
    f32x4 cR[6][2], cI[6][2];
    #pragma unroll
    for (int nt = 0; nt < 6; ++nt){
      float br = biasL[2*96 + nt*16 + col];
      float bi = biasL[3*96 + nt*16 + col];
      #pragma unroll
      for (int mt = 0; mt < 2; ++mt){
        cR[nt][mt] = (f32x4){br,br,br,br};
        cI[nt][mt] = (f32x4){bi,bi,bi,bi};
      }
    }
    #pragma unroll
    for (int nt = 0; nt < 6; ++nt)
      #pragma unroll
      for (int kt = 0; kt < 3; ++kt){
        bf16x8 Br = ldfrag(wfrag4, 2, nt, kt, ln);
        bf16x8 Bi = ldfrag(wfrag4, 3, nt, kt, ln);
        #pragma unroll
        for (int mt = 0; mt < 2; ++mt){
          cR[nt][mt] = __builtin_amdgcn_mfma_f32_16x16x32_bf16(Cr[mt][kt], Br, cR[nt][mt], 0,0,0);
          cR[nt][mt] = __builtin_amdgcn_mfma_f32_16x16x32_bf16(Cn[mt][kt], Bi, cR[nt][mt], 0,0,0);
          cI[nt][mt] = __builtin_amdgcn_mfma_f32_16x16x32_bf16(Ci[mt][kt], Br, cI[nt][mt], 0,0,0);
          cI[nt][mt] = __builtin_amdgcn_mfma_f32_16x16x32_bf16(Cr[mt][kt], Bi, cI[nt][mt], 0,0,0);
        }
      }
    // softshrink(v) = v - clamp(v, -L, L), then store packed to LDS
    const float L = 0.01f;
    #pragma unroll
    for (int nt = 0; nt < 6; ++nt)
      #pragma unroll
      for (int mt = 0; mt < 2; ++mt)
        #pragma unroll
        for (int rr = 0; rr < 4; ++rr){
          float vr = cR[nt][mt][rr]; vr = vr - fminf(fmaxf(vr, -L), L);
          float vi = cI[nt][mt][rr]; vi = vi - fminf(fmaxf(vi, -L), L);
          int pl = wv*32 + mt*16 + quad*4 + rr;
          xbuf[pl*97 + nt*16 + col] = pack_bf16(vr, vi);
        }
    __syncthreads();
    // coalesced copy back to band (in-place)
    for (int idx = tid; idx < 96*128; idx += 256){
      int o = idx >> 7, pl = idx & 127;
      int p = tile*128 + pl;
      if (p < NP) Abase[(size_t)o*NP + p] = xbuf[pl*97 + o];
    }
    __syncthreads();   // protect xbuf before next tile's layer-1 stores
  }
}

// ---------------- K4: inverse column FFT (zero-padded band) -> I2 ------------
__global__ __launch_bounds__(256, 4) void k4_icolfft(const unsigned* __restrict__ band,
                                                     unsigned* __restrict__ I2){
  __shared__ float2 tw[256];
  __shared__ float2 buf[16*272];
  int tid = threadIdx.x;
  build_tw(tw, tid);
  int wg = blockIdx.x; int b = wg / CC, c = wg % CC;
  int kb = c / BS, o = c % BS;
  const unsigned* ip = band + (size_t)((b*NB + kb)*BS + o) * NP;
  unsigned*       op = I2   + (size_t)(b*CC + c) * (YK*HH);
  int team = tid >> 4, u = tid & 15;
  for (int r = 0; r < 7; ++r){
    __syncthreads();
    for (int j = 0; j < 16; ++j){
      int y = r*16 + j;
      if (y < YK){
        float2 v = (tid >= XLO && tid < XHI) ? unpack_bf16(ip[y*NX + tid - XLO])
                                             : make_float2(0.0f, 0.0f);
        buf[j*272 + tid] = v;
      }
    }
    __syncthreads();
    c32 out[16];
    fft256_team_u<true>(tw, buf + team*272, u, out);
    int y = r*16 + team;
    if (y < YK){
      #pragma unroll
      for (int k2 = 0; k2 < 16; ++k2)
        op[y*HH + u + 16*k2] = pack_bf16(out[k2].re, out[k2].im);
    }
  }
}

// ---------------- K5: paired Hermitian inverse row FFT + 1/256 + residual ----
// Two real output rows per inverse FFT: Z[y] = A[y] + i*B[y]; since A,B are
// individually Hermitian, Z[256-y] = conj(A[y]) + i*conj(B[y]) is lane-local.
__global__ __launch_bounds__(256, 4) void k5_irowfft(const unsigned* __restrict__ I2,
                                                     const float* __restrict__ x,
                                                     float* __restrict__ outp){
  __shared__ float2 tw[256];
  __shared__ float2 buf[16*272];
  int tid = threadIdx.x;
  build_tw(tw, tid);
  int wg = blockIdx.x; int b = wg / CC, c = wg % CC;
  const unsigned* ip = I2   + (size_t)(b*CC + c) * (YK*HH);
  const float*    xp = x    + (size_t)(b*CC + c) * (HH*WW);
  float*          op = outp + (size_t)(b*CC + c) * (HH*WW);
  int team = tid >> 4, u = tid & 15;
  for (int r = 0; r < 8; ++r){
    __syncthreads();
    if (tid < YK){
      const uint4* rp = (const uint4*)(ip + (size_t)tid*HH + r*32);
      #pragma unroll
      for (int hf = 0; hf < 2; ++hf){
        uint4 q0 = rp[hf*4+0], q1 = rp[hf*4+1], q2 = rp[hf*4+2], q3 = rp[hf*4+3];
        unsigned qq[16] = {q0.x,q0.y,q0.z,q0.w, q1.x,q1.y,q1.z,q1.w,
                           q2.x,q2.y,q2.z,q2.w, q3.x,q3.y,q3.z,q3.w};
        #pragma unroll
        for (int jj = 0; jj < 8; ++jj){
          int j = hf*8 + jj;
          float2 a  = unpack_bf16(qq[2*jj]);      // A[y] (row h0 spectrum)
          float2 bb = unpack_bf16(qq[2*jj+1]);    // B[y] (row h1 spectrum)
          buf[j*272 + tid] = make_float2(a.x - bb.y, a.y + bb.x);          // Z[y]
          if (tid >= 1)
            buf[j*272 + 256 - tid] = make_float2(a.x + bb.y, bb.x - a.y);  // Z[256-y]
        }
      }
    } else if (tid <= 153){
      #pragma unroll
      for (int j = 0; j < 16; ++j)
        buf[j*272 + tid] = make_float2(0.0f, 0.0f);                        // zero band
    }
    __syncthreads();
    c32 out[16];
    fft256_team_u<true>(tw, buf + team*272, u, out);
    int h0 = r*32 + 2*team, h1 = h0 + 1;
    const float s = 1.0f/256.0f;
    #pragma unroll
    for (int k2 = 0; k2 < 16; ++k2){
      int w = u + 16*k2;
      op[h0*WW + w] = out[k2].re * s + xp[h0*WW + w];
      op[h1*WW + w] = out[k2].im * s + xp[h1*WW + w];
    }
  }
}

extern "C" void kernel_launch(void* const* d_in, const int* in_sizes, int n_in,
                              void* d_out, int out_size, void* d_ws, size_t ws_size,
                              hipStream_t stream){
  (void)in_sizes; (void)n_in; (void)out_size; (void)ws_size;
  const float* x  = (const float*)d_in[0];
  const float* w1 = (const float*)d_in[1];
  const float* b1 = (const float*)d_in[2];
  const float* w2 = (const float*)d_in[3];
  const float* b2 = (const float*)d_in[4];
  float* outp = (float*)d_out;

  // ws region: I1 (then reused as I2): 2*768*103*256 uints = 161,980,416 B
  unsigned* I12  = (unsigned*)d_ws;
  // band scratch lives in d_out (130 MB < 402 MB), consumed before K5 overwrites
  unsigned* band = (unsigned*)d_out;

  k1_rowfft <<<BB*CC, 256, 0, stream>>>(x, I12);
  k2_colfft <<<BB*CC, 256, 0, stream>>>(I12, band);
  dim3 g3(NT3G, BB*NB);
  k3_mix    <<<g3,    256, 0, stream>>>(band, w1, b1, w2, b2);
  k4_icolfft<<<BB*CC, 256, 0, stream>>>(band, I12);
  k5_irowfft<<<BB*CC, 256, 0, stream>>>(I12, x, outp);
}